// Round 20
// baseline (91.318 us; speedup 1.0000x reference)
//
#include <hip/hip_runtime.h>
#include <math.h>

// Problem constants
#define L_TOK 16384        // D*H*W tokens
#define C_DIM 96
#define N_HEADS 8
#define HD 12
#define D_DIM 16
#define HW_N 1024
#define HID_DIM 384
#define SCALE 0.2886751345948129f   // 12^-0.5
#define LOG2E 1.4426950408889634f   // folded with SCALE into q-rows of wq

typedef _Float16 h4 __attribute__((ext_vector_type(4)));
typedef __fp16 fp16x2 __attribute__((ext_vector_type(2)));   // cvt_pkrtz native type
typedef float v4f __attribute__((ext_vector_type(4)));

// native v_exp_f32 (2^x)
static __device__ __forceinline__ float fast_exp2(float x) {
#if __has_builtin(__builtin_amdgcn_exp2f)
    return __builtin_amdgcn_exp2f(x);
#else
    float r;
    asm("v_exp_f32 %0, %1" : "=v"(r) : "v"(x));
    return r;
#endif
}

// pack 4 floats -> h4 via two v_cvt_pkrtz_f16_f32
static __device__ __forceinline__ h4 pack4(float a, float b, float c, float d) {
    fp16x2 lo = __builtin_amdgcn_cvt_pkrtz(a, b);
    fp16x2 hi = __builtin_amdgcn_cvt_pkrtz(c, d);
    union { fp16x2 p[2]; h4 v; } u;
    u.p[0] = lo; u.p[1] = hi;
    return u.v;
}

// ---------------------------------------------------------------------------
// Merged prep kernel: blocks 0..63 = LN1; blocks 64..640 = weight convert.
// ---------------------------------------------------------------------------
__global__ __launch_bounds__(256) void prep_kernel(
    const float* __restrict__ x, const float* __restrict__ g1,
    const float* __restrict__ b1, _Float16* __restrict__ n1h,
    const float* __restrict__ qkv_hw_w, const float* __restrict__ qkv_t_w,
    const float* __restrict__ proj_hw_w, const float* __restrict__ proj_t_w,
    const float* __restrict__ proj_hw_b, const float* __restrict__ proj_t_b,
    const float* __restrict__ fc1_w, const float* __restrict__ fc2_w,
    _Float16* __restrict__ wq, _Float16* __restrict__ wp,
    _Float16* __restrict__ wf1, _Float16* __restrict__ wf2,
    float* __restrict__ bp) {
    if (blockIdx.x < 64) {
        int l = blockIdx.x * 256 + threadIdx.x;
        float v[C_DIM];
        float s = 0.f;
#pragma unroll
        for (int c = 0; c < C_DIM; c++) {
            v[c] = x[(size_t)c * L_TOK + l];
            s += v[c];
        }
        float mean = s * (1.f / C_DIM);
        float var = 0.f;
#pragma unroll
        for (int c = 0; c < C_DIM; c++) {
            float dd = v[c] - mean;
            var += dd * dd;
        }
        float r = rsqrtf(var * (1.f / C_DIM) + 1e-5f);
        _Float16* op = n1h + (size_t)l * C_DIM;
#pragma unroll
        for (int c = 0; c < C_DIM; c += 4) {
            h4 o;
            o[0] = (_Float16)((v[c + 0] - mean) * r * g1[c + 0] + b1[c + 0]);
            o[1] = (_Float16)((v[c + 1] - mean) * r * g1[c + 1] + b1[c + 1]);
            o[2] = (_Float16)((v[c + 2] - mean) * r * g1[c + 2] + b1[c + 2]);
            o[3] = (_Float16)((v[c + 3] - mean) * r * g1[c + 3] + b1[c + 3]);
            *(h4*)(op + c) = o;
        }
        return;
    }
    int idx = (blockIdx.x - 64) * 256 + threadIdx.x;
    if (idx < 55296) {
        int n = idx / 96;
        float v = (n < 288) ? qkv_hw_w[idx] : qkv_t_w[idx - 27648];
        bool isq = (n < 96) || (n >= 288 && n < 384);
        wq[idx] = (_Float16)(isq ? v * (SCALE * LOG2E) : v);
    } else if (idx < 55296 + 18432) {
        int i = idx - 55296;
        int n = i / 192, k = i % 192;
        float v = (k < 96) ? proj_hw_w[n * 96 + k] : proj_t_w[n * 96 + k - 96];
        wp[i] = (_Float16)v;
    } else if (idx < 73728 + 36864) {
        int i = idx - 73728;
        wf1[i] = (_Float16)fc1_w[i];
    } else if (idx < 110592 + 36864) {
        int i = idx - 110592;
        wf2[i] = (_Float16)fc2_w[i];
    } else if (idx < 147456 + 96) {
        int i = idx - 147456;
        bp[i] = proj_hw_b[i] + proj_t_b[i];
    }
}

// ---------------------------------------------------------------------------
#define GBM 64
#define GBN 48
#define GBK 96
#define LSTRIDE 104

// qkv GEMM with packed-scatter epilogue (R13-verified).
__global__ __launch_bounds__(256) void gemm_qkv(
    const _Float16* __restrict__ A, const _Float16* __restrict__ W,
    _Float16* __restrict__ Qp, _Float16* __restrict__ Kp,
    _Float16* __restrict__ VTp, _Float16* __restrict__ Tp) {
    __shared__ _Float16 As[GBM][LSTRIDE];
    __shared__ _Float16 Ws[GBN][LSTRIDE];
    const int t = threadIdx.x;
    const int m0 = blockIdx.x * GBM;
    const int n0 = blockIdx.y * GBN;
    const int lane = t & 63, w = t >> 6, g = lane >> 4, r = lane & 15;

    v4f acc[3];
#pragma unroll
    for (int nt = 0; nt < 3; nt++) {
        acc[nt][0] = 0.f; acc[nt][1] = 0.f; acc[nt][2] = 0.f; acc[nt][3] = 0.f;
    }
#pragma unroll
    for (int i = 0; i < 3; i++) {
        int idx = t + i * 256;
        int row = idx / 12, c = idx % 12;
        *(float4*)&As[row][c * 8] =
            *(const float4*)&A[(size_t)(m0 + row) * 96 + c * 8];
    }
#pragma unroll
    for (int i = 0; i < 3; i++) {
        int idx = t + i * 256;
        if (idx < 576) {
            int row = idx / 12, c = idx % 12;
            *(float4*)&Ws[row][c * 8] =
                *(const float4*)&W[(size_t)(n0 + row) * 96 + c * 8];
        }
    }
    __syncthreads();
#pragma unroll
    for (int ks = 0; ks < 6; ks++) {
        h4 af = *(const h4*)&As[w * 16 + r][ks * 16 + 4 * g];
#pragma unroll
        for (int nt = 0; nt < 3; nt++) {
            h4 wf = *(const h4*)&Ws[nt * 16 + r][ks * 16 + 4 * g];
            acc[nt] = __builtin_amdgcn_mfma_f32_16x16x16f16(wf, af, acc[nt], 0, 0, 0);
        }
    }

    const int m = m0 + w * 16 + r;
    const int d = m >> 10, hw = m & 1023;
    const int by = blockIdx.y;
#pragma unroll
    for (int nt = 0; nt < 3; nt++) {
        const int nb = n0 + nt * 16 + 4 * g;
        h4 ov;
        ov[0] = (_Float16)acc[nt][0]; ov[1] = (_Float16)acc[nt][1];
        ov[2] = (_Float16)acc[nt][2]; ov[3] = (_Float16)acc[nt][3];
        if (by < 2) {                      // Q
            int n = nb;
            int h = (unsigned)n / 12u, dd = n - h * 12;
            *(h4*)&Qp[((size_t)(d * 8 + h) * 1024 + hw) * 12 + dd] = ov;
        } else if (by < 4) {               // K
            int n = nb - 96;
            int h = (unsigned)n / 12u, dd = n - h * 12;
            *(h4*)&Kp[((size_t)(d * 8 + h) * 1024 + hw) * 12 + dd] = ov;
        } else if (by < 6) {               // V -> transposed scatter
            int n = nb - 192;
            int h = (unsigned)n / 12u, dd = n - h * 12;
#pragma unroll
            for (int j = 0; j < 4; j++) {
                VTp[((size_t)(d * 8 + h) * 12 + dd + j) * 1024 + hw] = ov[j];
            }
        } else {                           // T (q_t/k_t/v_t)
            *(h4*)&Tp[(size_t)(hw * 16 + d) * 288 + (nb - 288)] = ov;
        }
    }
}

// ---------------------------------------------------------------------------
// FUSED MLP v6 (R19-verified): 32 rows/block, 4 waves (mi,ni), grid 512,
// 2 blocks/CU. Register chain + small-LDS cross-ni hops.
// ---------------------------------------------------------------------------
#define WSTRIDE 104

#define STAGE(buf, src, stride)                                              \
    {                                                                        \
        _Pragma("unroll")                                                    \
        for (int i_ = 0; i_ < 5; i_++) {                                     \
            int idx_ = t + i_ * 256;                                         \
            if (idx_ < 1152) {                                               \
                int row_ = idx_ / 12, c_ = idx_ % 12;                        \
                *(float4*)&Wb[buf][row_ * WSTRIDE + c_ * 8] =                \
                    *(const float4*)&(src)[(size_t)row_ * (stride) + c_ * 8];\
            }                                                                \
        }                                                                    \
    }

#define PROJ_CHUNK(buf, kc)                                                  \
    {                                                                        \
        _Pragma("unroll")                                                    \
        for (int ks = 0; ks < 6; ks++) {                                     \
            _Pragma("unroll")                                                \
            for (int nt = 0; nt < 3; nt++) {                                 \
                h4 wf = *(const h4*)&Wb[buf][(ni * 48 + nt * 16 + r) *       \
                                             WSTRIDE + ks * 16 + 4 * g];     \
                acc[nt] = __builtin_amdgcn_mfma_f32_16x16x16f16(             \
                    wf, afp[kc][ks], acc[nt], 0, 0, 0);                      \
            }                                                                \
        }                                                                    \
    }

#define FC1_CHUNK(buf, nc)                                                   \
    {                                                                        \
        v4f f[3];                                                            \
        _Pragma("unroll")                                                    \
        for (int nt = 0; nt < 3; nt++) {                                     \
            f[nt][0] = 0.f; f[nt][1] = 0.f; f[nt][2] = 0.f; f[nt][3] = 0.f;  \
        }                                                                    \
        _Pragma("unroll")                                                    \
        for (int ks = 0; ks < 6; ks++) {                                     \
            h4 af = *(const h4*)&n2_lds[(mi * 16 + r) * WSTRIDE +            \
                                        ks * 16 + 4 * g];                    \
            _Pragma("unroll")                                                \
            for (int nt = 0; nt < 3; nt++) {                                 \
                h4 wf = *(const h4*)&Wb[buf][(ni * 48 + nt * 16 + r) *       \
                                             WSTRIDE + ks * 16 + 4 * g];     \
                f[nt] = __builtin_amdgcn_mfma_f32_16x16x16f16(               \
                    wf, af, f[nt], 0, 0, 0);                                 \
            }                                                                \
        }                                                                    \
        _Pragma("unroll")                                                    \
        for (int nt = 0; nt < 3; nt++) {                                     \
            const int nb = (nc) * 96 + ni * 48 + nt * 16 + 4 * g;            \
            float4 bv = *(const float4*)&f1b[nb];                            \
            float u0 = f[nt][0] + bv.x, u1 = f[nt][1] + bv.y;                \
            float u2 = f[nt][2] + bv.z, u3 = f[nt][3] + bv.w;                \
            hf[nc][nt] =                                                     \
                pack4(0.5f * u0 * (1.f + erff(u0 * 0.7071067811865476f)),    \
                      0.5f * u1 * (1.f + erff(u1 * 0.7071067811865476f)),    \
                      0.5f * u2 * (1.f + erff(u2 * 0.7071067811865476f)),    \
                      0.5f * u3 * (1.f + erff(u3 * 0.7071067811865476f)));   \
        }                                                                    \
    }

#define FC2_CHUNK(buf, kc)                                                   \
    {                                                                        \
        _Pragma("unroll")                                                    \
        for (int ks = 0; ks < 3; ks++) {                                     \
            _Pragma("unroll")                                                \
            for (int nt = 0; nt < 6; nt++) {                                 \
                h4 wf = *(const h4*)&Wb[buf][(nt * 16 + r) * WSTRIDE +       \
                                             ni * 48 + ks * 16 + 4 * g];     \
                o6[nt] = __builtin_amdgcn_mfma_f32_16x16x16f16(              \
                    wf, hf[kc][ks], o6[nt], 0, 0, 0);                        \
            }                                                                \
        }                                                                    \
    }

__global__ __launch_bounds__(256) void fused_mlp(
    const _Float16* __restrict__ A, const _Float16* __restrict__ wp,
    const float* __restrict__ bp, const float* __restrict__ x,
    const float* __restrict__ g2, const float* __restrict__ b2,
    const _Float16* __restrict__ wf1, const float* __restrict__ f1b,
    const _Float16* __restrict__ wf2, const float* __restrict__ f2b,
    float* __restrict__ out) {
    __shared__ _Float16 Wb[2][96 * WSTRIDE];     // 2 x 19968 B
    __shared__ _Float16 n2_lds[32 * WSTRIDE];    // 6656 B
    __shared__ float sh[96 * 34];                // 13056 B
    __shared__ float red[2][32][2];              // 512 B

    const int t = threadIdx.x;
    const int bx = blockIdx.x;
    const int bxs = (bx & 7) * 64 + (bx >> 3);   // XCD write-grouping (512=8x64)
    const int m0 = bxs * 32;
    const int lane = t & 63, w = t >> 6, g = lane >> 4, r = lane & 15;
    const int mi = w >> 1, ni = w & 1;
    const int rl = mi * 16 + r;
    const int m = m0 + rl;

    h4 afp[2][6];
#pragma unroll
    for (int kc = 0; kc < 2; kc++)
#pragma unroll
        for (int ks = 0; ks < 6; ks++)
            afp[kc][ks] =
                *(const h4*)&A[(size_t)m * 192 + kc * 96 + ks * 16 + 4 * g];
    float xr[12];
#pragma unroll
    for (int nt = 0; nt < 3; nt++) {
#pragma unroll
        for (int j = 0; j < 4; j++)
            xr[nt * 4 + j] =
                x[(size_t)(ni * 48 + nt * 16 + 4 * g + j) * L_TOK + m];
    }

    STAGE(0, wp, 192);
    __syncthreads();
    STAGE(1, wp + 96, 192);
    v4f acc[3];
#pragma unroll
    for (int nt = 0; nt < 3; nt++) {
        acc[nt][0] = 0.f; acc[nt][1] = 0.f; acc[nt][2] = 0.f; acc[nt][3] = 0.f;
    }
    PROJ_CHUNK(0, 0);
    __syncthreads();
    STAGE(0, wf1, 96);
    PROJ_CHUNK(1, 1);
    float v[12];
    float s1 = 0.f, s2 = 0.f;
#pragma unroll
    for (int nt = 0; nt < 3; nt++) {
        const int c = ni * 48 + nt * 16 + 4 * g;
        float4 bv = *(const float4*)&bp[c];
        float a0 = acc[nt][0] + bv.x + xr[nt * 4 + 0];
        float a1 = acc[nt][1] + bv.y + xr[nt * 4 + 1];
        float a2 = acc[nt][2] + bv.z + xr[nt * 4 + 2];
        float a3 = acc[nt][3] + bv.w + xr[nt * 4 + 3];
        v[nt * 4 + 0] = a0; v[nt * 4 + 1] = a1;
        v[nt * 4 + 2] = a2; v[nt * 4 + 3] = a3;
        s1 += (a0 + a1) + (a2 + a3);
        s2 += (a0 * a0 + a1 * a1) + (a2 * a2 + a3 * a3);
    }
    s1 += __shfl_xor(s1, 16, 64);
    s1 += __shfl_xor(s1, 32, 64);
    s2 += __shfl_xor(s2, 16, 64);
    s2 += __shfl_xor(s2, 32, 64);
    if (g == 0) { red[ni][rl][0] = s1; red[ni][rl][1] = s2; }
    __syncthreads();
    {
        float t1 = red[0][rl][0] + red[1][rl][0];
        float t2 = red[0][rl][1] + red[1][rl][1];
        float mean = t1 * (1.f / 96.f);
        float var = t2 * (1.f / 96.f) - mean * mean;
        float rstd = rsqrtf(var + 1e-5f);
#pragma unroll
        for (int nt = 0; nt < 3; nt++) {
            const int c = ni * 48 + nt * 16 + 4 * g;
            float4 gg = *(const float4*)&g2[c];
            float4 bb = *(const float4*)&b2[c];
            h4 o = pack4((v[nt * 4 + 0] - mean) * rstd * gg.x + bb.x,
                         (v[nt * 4 + 1] - mean) * rstd * gg.y + bb.y,
                         (v[nt * 4 + 2] - mean) * rstd * gg.z + bb.z,
                         (v[nt * 4 + 3] - mean) * rstd * gg.w + bb.w);
            *(h4*)&n2_lds[rl * WSTRIDE + c] = o;
        }
    }
    STAGE(1, wf1 + 96 * 96, 96);
    __syncthreads();
    h4 hf[4][3];
    FC1_CHUNK(0, 0);
    __syncthreads();
    STAGE(0, wf1 + 2 * 96 * 96, 96);
    FC1_CHUNK(1, 1);
    __syncthreads();
    STAGE(1, wf1 + 3 * 96 * 96, 96);
    FC1_CHUNK(0, 2);
    __syncthreads();
    STAGE(0, wf2, 384);
    FC1_CHUNK(1, 3);
    __syncthreads();
    v4f o6[6];
#pragma unroll
    for (int nt = 0; nt < 6; nt++) {
        o6[nt][0] = 0.f; o6[nt][1] = 0.f; o6[nt][2] = 0.f; o6[nt][3] = 0.f;
    }
    STAGE(1, wf2 + 96, 384);
    FC2_CHUNK(0, 0);
    __syncthreads();
    STAGE(0, wf2 + 192, 384);
    FC2_CHUNK(1, 1);
    __syncthreads();
    STAGE(1, wf2 + 288, 384);
    FC2_CHUNK(0, 2);
    __syncthreads();
    FC2_CHUNK(1, 3);
    __syncthreads();

    if (ni == 0) {
#pragma unroll
        for (int nt = 0; nt < 6; nt++) {
#pragma unroll
            for (int j = 0; j < 4; j++) {
                const int c = nt * 16 + 4 * g + j;
                float val = o6[nt][j] + f2b[c];
                if (nt < 3) val += v[nt * 4 + j];
                sh[c * 34 + rl] = val;
            }
        }
    }
    __syncthreads();
    if (ni == 1) {
#pragma unroll
        for (int nt = 0; nt < 6; nt++) {
#pragma unroll
            for (int j = 0; j < 4; j++) {
                const int c = nt * 16 + 4 * g + j;
                float val = o6[nt][j];
                if (nt >= 3) val += v[(nt - 3) * 4 + j];
                sh[c * 34 + rl] += val;
            }
        }
    }
    __syncthreads();
    const int hh = m0 >> 9, ww0 = (m0 >> 4) & 31;
#pragma unroll
    for (int i = 0; i < 6; i++) {
        int task = t + i * 256;
        int n = task >> 4, dd = task & 15;
        float2 ov;
        ov.x = sh[n * 34 + dd];
        ov.y = sh[n * 34 + 16 + dd];
        *(float2*)&out[(size_t)n * L_TOK + dd * 1024 + hh * 32 + ww0] = ov;
    }
}

// ---------------------------------------------------------------------------
// HW attention v3: XCD-local slice grid (R18) + K read DIRECTLY from L2
// (no K_lds). With all 8 qb-blocks of a slice on one XCD, the 24KB K panel
// is L2-hot after block 1 -> staging it to LDS was redundant. LDS drops
// 51.7 -> 26.9 KB and VGPR stays ~110 -> 4 blocks/CU = 16 waves/CU
// (was 3/12). unroll-4 kt loop keeps 4 independent K loads in flight.
// ---------------------------------------------------------------------------
__global__ __launch_bounds__(256) void attn_hw_kernel(
    const _Float16* __restrict__ Qp, const _Float16* __restrict__ Kp,
    const _Float16* __restrict__ VTp, _Float16* __restrict__ o_cat) {
    __shared__ _Float16 VT_lds[13 * 1032];       // 26832 B (only V^T staged)
    const int t = threadIdx.x;
    const int sliceid = blockIdx.x;              // 0..127 = d*8+h
    const int qb = blockIdx.y;                   // 0..7
    const int d = sliceid >> 3, h = sliceid & 7;
    const size_t tokbase = (size_t)d * HW_N;
    const int hoff = h * HD;
    const size_t slice = (size_t)sliceid;

    {
        const float4* Vg = (const float4*)(VTp + slice * 12288);
#pragma unroll
        for (int i = 0; i < 6; i++) {
            int off = t + i * 256;
            int row = off >> 7, col = (off & 127) * 8;
            *(float4*)&VT_lds[row * 1032 + col] = Vg[off];
        }
        // ones-row (f16 1.0 = 0x3C00): D row 12 becomes the softmax denom
        unsigned* zp = (unsigned*)&VT_lds[12 * 1032];
        zp[t] = 0x3C003C00u; zp[t + 256] = 0x3C003C00u;
        if (t < 4) zp[t + 512] = 0x3C003C00u;
    }

    const int lane = t & 63, w = t >> 6, g = lane >> 4, r = lane & 15;
    const int q0w = qb * 128 + w * 32;

    h4 zf; zf[0] = zf[1] = zf[2] = zf[3] = (_Float16)0.f;
    h4 qf[2];
    {
        const _Float16* Qbase = Qp + (slice * 1024 + q0w + r) * 12 + 4 * g;
#pragma unroll
        for (int qt = 0; qt < 2; qt++) {
            qf[qt] = (g < 3) ? *(const h4*)(Qbase + qt * 16 * 12) : zf;
        }
    }

    v4f acc[2];
#pragma unroll
    for (int qt = 0; qt < 2; qt++) {
        acc[qt][0] = acc[qt][1] = acc[qt][2] = acc[qt][3] = 0.f;
    }

    // K read per-tile straight from global (L2-hot, XCD-local)
    const _Float16* kptr = Kp + slice * 12288 + r * 12 + 4 * g;
    const int rowc = (r < 12) ? r : 12;
    const int voff = rowc * 1032 + 4 * g;

    __syncthreads();

    v4f zero; zero[0] = zero[1] = zero[2] = zero[3] = 0.f;
#pragma unroll 4
    for (int kt = 0; kt < HW_N / 16; kt++) {
        h4 kf = (g < 3) ? *(const h4*)(kptr + kt * 192) : zf;
        h4 vf = *(const h4*)&VT_lds[voff + kt * 16];
#pragma unroll
        for (int qt = 0; qt < 2; qt++) {
            v4f s = __builtin_amdgcn_mfma_f32_16x16x16f16(kf, qf[qt], zero, 0, 0, 0);
            h4 pf = pack4(fast_exp2(s[0]), fast_exp2(s[1]),
                          fast_exp2(s[2]), fast_exp2(s[3]));
            acc[qt] = __builtin_amdgcn_mfma_f32_16x16x16f16(vf, pf, acc[qt], 0, 0, 0);
        }
    }

#pragma unroll
    for (int qt = 0; qt < 2; qt++) {
        float denom = __shfl(acc[qt][0], 48 + r, 64);
        float rs = 1.f / denom;
        if (g < 3) {
            _Float16* op =
                o_cat + (tokbase + q0w + qt * 16 + r) * 192 + hoff + 4 * g;
            h4 o;
            o[0] = (_Float16)(acc[qt][0] * rs);
            o[1] = (_Float16)(acc[qt][1] * rs);
            o[2] = (_Float16)(acc[qt][2] * rs);
            o[3] = (_Float16)(acc[qt][3] * rs);
            *(h4*)op = o;
        }
    }
}

// ---------------------------------------------------------------------------
// Temporal attention from T_pack.
// ---------------------------------------------------------------------------
__global__ __launch_bounds__(256) void attn_t_kernel(
    const _Float16* __restrict__ Tp, _Float16* __restrict__ o_cat) {
    int gid = blockIdx.x * 256 + threadIdx.x;
    int hw = gid >> 7;
    int h = (gid >> 4) & 7;
    int q = gid & 15;
    const int hoff = h * HD;
    const _Float16* base = Tp + (size_t)(hw * 16) * 288;

    float qr[HD];
    {
        const _Float16* p = base + q * 288 + hoff;
        h4 a = *(const h4*)p, b = *(const h4*)(p + 4), c = *(const h4*)(p + 8);
#pragma unroll
        for (int e = 0; e < 4; e++) {
            qr[e] = (float)a[e]; qr[4 + e] = (float)b[e]; qr[8 + e] = (float)c[e];
        }
    }
    float s[D_DIM];
    float mx = -1e30f;
#pragma unroll
    for (int j = 0; j < D_DIM; j++) {
        const _Float16* kp = base + j * 288 + 96 + hoff;
        h4 a = *(const h4*)kp, b = *(const h4*)(kp + 4), c = *(const h4*)(kp + 8);
        float dot = 0.f;
#pragma unroll
        for (int e = 0; e < 4; e++) {
            dot += qr[e] * (float)a[e] + qr[4 + e] * (float)b[e] +
                   qr[8 + e] * (float)c[e];
        }
        s[j] = dot;
        mx = fmaxf(mx, dot);
    }
    float sum = 0.f;
#pragma unroll
    for (int j = 0; j < D_DIM; j++) {
        s[j] = fast_exp2(s[j] - mx);
        sum += s[j];
    }
    float rs = 1.f / sum;
    float o[HD];
#pragma unroll
    for (int e = 0; e < HD; e++) o[e] = 0.f;
#pragma unroll
    for (int j = 0; j < D_DIM; j++) {
        const _Float16* vp = base + j * 288 + 192 + hoff;
        h4 a = *(const h4*)vp, b = *(const h4*)(vp + 4), c = *(const h4*)(vp + 8);
        float p = s[j];
#pragma unroll
        for (int e = 0; e < 4; e++) {
            o[e] += p * (float)a[e];
            o[4 + e] += p * (float)b[e];
            o[8 + e] += p * (float)c[e];
        }
    }
    _Float16* op = o_cat + ((size_t)hw * D_DIM + q) * 192 + 96 + hoff;
#pragma unroll
    for (int e = 0; e < HD; e += 4) {
        h4 a;
        a[0] = (_Float16)(o[e] * rs); a[1] = (_Float16)(o[e + 1] * rs);
        a[2] = (_Float16)(o[e + 2] * rs); a[3] = (_Float16)(o[e + 3] * rs);
        *(h4*)(op + e) = a;
    }
}

// ---------------------------------------------------------------------------
extern "C" void kernel_launch(void* const* d_in, const int* in_sizes, int n_in,
                              void* d_out, int out_size, void* d_ws,
                              size_t ws_size, hipStream_t stream) {
    const float* x         = (const float*)d_in[0];
    const float* norm1_g   = (const float*)d_in[1];
    const float* norm1_b   = (const float*)d_in[2];
    const float* qkv_hw_w  = (const float*)d_in[3];
    const float* proj_hw_w = (const float*)d_in[4];
    const float* proj_hw_b = (const float*)d_in[5];
    const float* qkv_t_w   = (const float*)d_in[6];
    const float* proj_t_w  = (const float*)d_in[7];
    const float* proj_t_b  = (const float*)d_in[8];
    const float* norm2_g   = (const float*)d_in[9];
    const float* norm2_b   = (const float*)d_in[10];
    const float* fc1_w     = (const float*)d_in[11];
    const float* fc1_b     = (const float*)d_in[12];
    const float* fc2_w     = (const float*)d_in[13];
    const float* fc2_b     = (const float*)d_in[14];
    float* out = (float*)d_out;

    // workspace layout
    char* ws = (char*)d_ws;
    _Float16* n1h    = (_Float16*)ws;                          // L*96 f16
    _Float16* o_cat  = n1h + (size_t)L_TOK * C_DIM;            // L*192 f16
    float*    out_res= (float*)(o_cat + (size_t)L_TOK * 192);  // (unused)
    _Float16* packs  = (_Float16*)(out_res + (size_t)L_TOK * C_DIM);
    _Float16* Qp     = packs;                                  // 16*8*1024*12
    _Float16* Kp     = Qp + 1572864;
    _Float16* VTp    = Kp + 1572864;
    _Float16* Tp     = VTp + 1572864;                          // L*288
    _Float16* wq     = Tp + (size_t)L_TOK * 288;               // 55296
    _Float16* wp     = wq + 55296;
    _Float16* wf1    = wp + 18432;
    _Float16* wf2    = wf1 + 36864;
    float*    bp     = (float*)(wf2 + 36864);

    // 1. LN1 + weight convert (merged)
    prep_kernel<<<641, 256, 0, stream>>>(x, norm1_g, norm1_b, n1h,
                                         qkv_hw_w, qkv_t_w, proj_hw_w,
                                         proj_t_w, proj_hw_b, proj_t_b,
                                         fc1_w, fc2_w, wq, wp, wf1, wf2, bp);
    // 2. fused qkv GEMM with packed scatter
    gemm_qkv<<<dim3(L_TOK / GBM, 576 / GBN), 256, 0, stream>>>(
        n1h, wq, Qp, Kp, VTp, Tp);
    // 3. HW attention (XCD-local staging; K direct from L2)
    attn_hw_kernel<<<dim3(128, 8), 256, 0, stream>>>(Qp, Kp, VTp, o_cat);
    // 4. T attention
    attn_t_kernel<<<(HW_N * N_HEADS * D_DIM) / 256, 256, 0, stream>>>(Tp, o_cat);
    // 5. fused MLP v6
    fused_mlp<<<512, 256, 0, stream>>>(
        o_cat, wp, bp, x, norm2_g, norm2_b, wf1, fc1_b, wf2, fc2_b, out);
}

// Round 21
// 87.392 us; speedup vs baseline: 1.0449x; 1.0449x over previous
//
#include <hip/hip_runtime.h>
#include <math.h>

// Problem constants
#define L_TOK 16384        // D*H*W tokens
#define C_DIM 96
#define N_HEADS 8
#define HD 12
#define D_DIM 16
#define HW_N 1024
#define HID_DIM 384
#define SCALE 0.2886751345948129f   // 12^-0.5
#define LOG2E 1.4426950408889634f   // folded with SCALE into q-rows of wq

typedef _Float16 h4 __attribute__((ext_vector_type(4)));
typedef __fp16 fp16x2 __attribute__((ext_vector_type(2)));   // cvt_pkrtz native type
typedef float v4f __attribute__((ext_vector_type(4)));

// native v_exp_f32 (2^x)
static __device__ __forceinline__ float fast_exp2(float x) {
#if __has_builtin(__builtin_amdgcn_exp2f)
    return __builtin_amdgcn_exp2f(x);
#else
    float r;
    asm("v_exp_f32 %0, %1" : "=v"(r) : "v"(x));
    return r;
#endif
}

// pack 4 floats -> h4 via two v_cvt_pkrtz_f16_f32
static __device__ __forceinline__ h4 pack4(float a, float b, float c, float d) {
    fp16x2 lo = __builtin_amdgcn_cvt_pkrtz(a, b);
    fp16x2 hi = __builtin_amdgcn_cvt_pkrtz(c, d);
    union { fp16x2 p[2]; h4 v; } u;
    u.p[0] = lo; u.p[1] = hi;
    return u.v;
}

// ---------------------------------------------------------------------------
// Merged prep kernel: blocks 0..63 = LN1; blocks 64..640 = weight convert.
// ---------------------------------------------------------------------------
__global__ __launch_bounds__(256) void prep_kernel(
    const float* __restrict__ x, const float* __restrict__ g1,
    const float* __restrict__ b1, _Float16* __restrict__ n1h,
    const float* __restrict__ qkv_hw_w, const float* __restrict__ qkv_t_w,
    const float* __restrict__ proj_hw_w, const float* __restrict__ proj_t_w,
    const float* __restrict__ proj_hw_b, const float* __restrict__ proj_t_b,
    const float* __restrict__ fc1_w, const float* __restrict__ fc2_w,
    _Float16* __restrict__ wq, _Float16* __restrict__ wp,
    _Float16* __restrict__ wf1, _Float16* __restrict__ wf2,
    float* __restrict__ bp) {
    if (blockIdx.x < 64) {
        int l = blockIdx.x * 256 + threadIdx.x;
        float v[C_DIM];
        float s = 0.f;
#pragma unroll
        for (int c = 0; c < C_DIM; c++) {
            v[c] = x[(size_t)c * L_TOK + l];
            s += v[c];
        }
        float mean = s * (1.f / C_DIM);
        float var = 0.f;
#pragma unroll
        for (int c = 0; c < C_DIM; c++) {
            float dd = v[c] - mean;
            var += dd * dd;
        }
        float r = rsqrtf(var * (1.f / C_DIM) + 1e-5f);
        _Float16* op = n1h + (size_t)l * C_DIM;
#pragma unroll
        for (int c = 0; c < C_DIM; c += 4) {
            h4 o;
            o[0] = (_Float16)((v[c + 0] - mean) * r * g1[c + 0] + b1[c + 0]);
            o[1] = (_Float16)((v[c + 1] - mean) * r * g1[c + 1] + b1[c + 1]);
            o[2] = (_Float16)((v[c + 2] - mean) * r * g1[c + 2] + b1[c + 2]);
            o[3] = (_Float16)((v[c + 3] - mean) * r * g1[c + 3] + b1[c + 3]);
            *(h4*)(op + c) = o;
        }
        return;
    }
    int idx = (blockIdx.x - 64) * 256 + threadIdx.x;
    if (idx < 55296) {
        int n = idx / 96;
        float v = (n < 288) ? qkv_hw_w[idx] : qkv_t_w[idx - 27648];
        bool isq = (n < 96) || (n >= 288 && n < 384);
        wq[idx] = (_Float16)(isq ? v * (SCALE * LOG2E) : v);
    } else if (idx < 55296 + 18432) {
        int i = idx - 55296;
        int n = i / 192, k = i % 192;
        float v = (k < 96) ? proj_hw_w[n * 96 + k] : proj_t_w[n * 96 + k - 96];
        wp[i] = (_Float16)v;
    } else if (idx < 73728 + 36864) {
        int i = idx - 73728;
        wf1[i] = (_Float16)fc1_w[i];
    } else if (idx < 110592 + 36864) {
        int i = idx - 110592;
        wf2[i] = (_Float16)fc2_w[i];
    } else if (idx < 147456 + 96) {
        int i = idx - 147456;
        bp[i] = proj_hw_b[i] + proj_t_b[i];
    }
}

// ---------------------------------------------------------------------------
#define GBM 64
#define GBN 48
#define GBK 96
#define LSTRIDE 104

// qkv GEMM with packed-scatter epilogue (R13-verified).
__global__ __launch_bounds__(256) void gemm_qkv(
    const _Float16* __restrict__ A, const _Float16* __restrict__ W,
    _Float16* __restrict__ Qp, _Float16* __restrict__ Kp,
    _Float16* __restrict__ VTp, _Float16* __restrict__ Tp) {
    __shared__ _Float16 As[GBM][LSTRIDE];
    __shared__ _Float16 Ws[GBN][LSTRIDE];
    const int t = threadIdx.x;
    const int m0 = blockIdx.x * GBM;
    const int n0 = blockIdx.y * GBN;
    const int lane = t & 63, w = t >> 6, g = lane >> 4, r = lane & 15;

    v4f acc[3];
#pragma unroll
    for (int nt = 0; nt < 3; nt++) {
        acc[nt][0] = 0.f; acc[nt][1] = 0.f; acc[nt][2] = 0.f; acc[nt][3] = 0.f;
    }
#pragma unroll
    for (int i = 0; i < 3; i++) {
        int idx = t + i * 256;
        int row = idx / 12, c = idx % 12;
        *(float4*)&As[row][c * 8] =
            *(const float4*)&A[(size_t)(m0 + row) * 96 + c * 8];
    }
#pragma unroll
    for (int i = 0; i < 3; i++) {
        int idx = t + i * 256;
        if (idx < 576) {
            int row = idx / 12, c = idx % 12;
            *(float4*)&Ws[row][c * 8] =
                *(const float4*)&W[(size_t)(n0 + row) * 96 + c * 8];
        }
    }
    __syncthreads();
#pragma unroll
    for (int ks = 0; ks < 6; ks++) {
        h4 af = *(const h4*)&As[w * 16 + r][ks * 16 + 4 * g];
#pragma unroll
        for (int nt = 0; nt < 3; nt++) {
            h4 wf = *(const h4*)&Ws[nt * 16 + r][ks * 16 + 4 * g];
            acc[nt] = __builtin_amdgcn_mfma_f32_16x16x16f16(wf, af, acc[nt], 0, 0, 0);
        }
    }

    const int m = m0 + w * 16 + r;
    const int d = m >> 10, hw = m & 1023;
    const int by = blockIdx.y;
#pragma unroll
    for (int nt = 0; nt < 3; nt++) {
        const int nb = n0 + nt * 16 + 4 * g;
        h4 ov;
        ov[0] = (_Float16)acc[nt][0]; ov[1] = (_Float16)acc[nt][1];
        ov[2] = (_Float16)acc[nt][2]; ov[3] = (_Float16)acc[nt][3];
        if (by < 2) {                      // Q
            int n = nb;
            int h = (unsigned)n / 12u, dd = n - h * 12;
            *(h4*)&Qp[((size_t)(d * 8 + h) * 1024 + hw) * 12 + dd] = ov;
        } else if (by < 4) {               // K
            int n = nb - 96;
            int h = (unsigned)n / 12u, dd = n - h * 12;
            *(h4*)&Kp[((size_t)(d * 8 + h) * 1024 + hw) * 12 + dd] = ov;
        } else if (by < 6) {               // V -> transposed scatter
            int n = nb - 192;
            int h = (unsigned)n / 12u, dd = n - h * 12;
#pragma unroll
            for (int j = 0; j < 4; j++) {
                VTp[((size_t)(d * 8 + h) * 12 + dd + j) * 1024 + hw] = ov[j];
            }
        } else {                           // T (q_t/k_t/v_t)
            *(h4*)&Tp[(size_t)(hw * 16 + d) * 288 + (nb - 288)] = ov;
        }
    }
}

// ---------------------------------------------------------------------------
// FUSED MLP v6 (R19-verified): 32 rows/block, 4 waves (mi,ni), grid 512,
// 2 blocks/CU. Register chain + small-LDS cross-ni hops.
// ---------------------------------------------------------------------------
#define WSTRIDE 104

#define STAGE(buf, src, stride)                                              \
    {                                                                        \
        _Pragma("unroll")                                                    \
        for (int i_ = 0; i_ < 5; i_++) {                                     \
            int idx_ = t + i_ * 256;                                         \
            if (idx_ < 1152) {                                               \
                int row_ = idx_ / 12, c_ = idx_ % 12;                        \
                *(float4*)&Wb[buf][row_ * WSTRIDE + c_ * 8] =                \
                    *(const float4*)&(src)[(size_t)row_ * (stride) + c_ * 8];\
            }                                                                \
        }                                                                    \
    }

#define PROJ_CHUNK(buf, kc)                                                  \
    {                                                                        \
        _Pragma("unroll")                                                    \
        for (int ks = 0; ks < 6; ks++) {                                     \
            _Pragma("unroll")                                                \
            for (int nt = 0; nt < 3; nt++) {                                 \
                h4 wf = *(const h4*)&Wb[buf][(ni * 48 + nt * 16 + r) *       \
                                             WSTRIDE + ks * 16 + 4 * g];     \
                acc[nt] = __builtin_amdgcn_mfma_f32_16x16x16f16(             \
                    wf, afp[kc][ks], acc[nt], 0, 0, 0);                      \
            }                                                                \
        }                                                                    \
    }

#define FC1_CHUNK(buf, nc)                                                   \
    {                                                                        \
        v4f f[3];                                                            \
        _Pragma("unroll")                                                    \
        for (int nt = 0; nt < 3; nt++) {                                     \
            f[nt][0] = 0.f; f[nt][1] = 0.f; f[nt][2] = 0.f; f[nt][3] = 0.f;  \
        }                                                                    \
        _Pragma("unroll")                                                    \
        for (int ks = 0; ks < 6; ks++) {                                     \
            h4 af = *(const h4*)&n2_lds[(mi * 16 + r) * WSTRIDE +            \
                                        ks * 16 + 4 * g];                    \
            _Pragma("unroll")                                                \
            for (int nt = 0; nt < 3; nt++) {                                 \
                h4 wf = *(const h4*)&Wb[buf][(ni * 48 + nt * 16 + r) *       \
                                             WSTRIDE + ks * 16 + 4 * g];     \
                f[nt] = __builtin_amdgcn_mfma_f32_16x16x16f16(               \
                    wf, af, f[nt], 0, 0, 0);                                 \
            }                                                                \
        }                                                                    \
        _Pragma("unroll")                                                    \
        for (int nt = 0; nt < 3; nt++) {                                     \
            const int nb = (nc) * 96 + ni * 48 + nt * 16 + 4 * g;            \
            float4 bv = *(const float4*)&f1b[nb];                            \
            float u0 = f[nt][0] + bv.x, u1 = f[nt][1] + bv.y;                \
            float u2 = f[nt][2] + bv.z, u3 = f[nt][3] + bv.w;                \
            hf[nc][nt] =                                                     \
                pack4(0.5f * u0 * (1.f + erff(u0 * 0.7071067811865476f)),    \
                      0.5f * u1 * (1.f + erff(u1 * 0.7071067811865476f)),    \
                      0.5f * u2 * (1.f + erff(u2 * 0.7071067811865476f)),    \
                      0.5f * u3 * (1.f + erff(u3 * 0.7071067811865476f)));   \
        }                                                                    \
    }

#define FC2_CHUNK(buf, kc)                                                   \
    {                                                                        \
        _Pragma("unroll")                                                    \
        for (int ks = 0; ks < 3; ks++) {                                     \
            _Pragma("unroll")                                                \
            for (int nt = 0; nt < 6; nt++) {                                 \
                h4 wf = *(const h4*)&Wb[buf][(nt * 16 + r) * WSTRIDE +       \
                                             ni * 48 + ks * 16 + 4 * g];     \
                o6[nt] = __builtin_amdgcn_mfma_f32_16x16x16f16(              \
                    wf, hf[kc][ks], o6[nt], 0, 0, 0);                        \
            }                                                                \
        }                                                                    \
    }

__global__ __launch_bounds__(256) void fused_mlp(
    const _Float16* __restrict__ A, const _Float16* __restrict__ wp,
    const float* __restrict__ bp, const float* __restrict__ x,
    const float* __restrict__ g2, const float* __restrict__ b2,
    const _Float16* __restrict__ wf1, const float* __restrict__ f1b,
    const _Float16* __restrict__ wf2, const float* __restrict__ f2b,
    float* __restrict__ out) {
    __shared__ _Float16 Wb[2][96 * WSTRIDE];     // 2 x 19968 B
    __shared__ _Float16 n2_lds[32 * WSTRIDE];    // 6656 B
    __shared__ float sh[96 * 34];                // 13056 B
    __shared__ float red[2][32][2];              // 512 B

    const int t = threadIdx.x;
    const int bx = blockIdx.x;
    const int bxs = (bx & 7) * 64 + (bx >> 3);   // XCD write-grouping (512=8x64)
    const int m0 = bxs * 32;
    const int lane = t & 63, w = t >> 6, g = lane >> 4, r = lane & 15;
    const int mi = w >> 1, ni = w & 1;
    const int rl = mi * 16 + r;
    const int m = m0 + rl;

    h4 afp[2][6];
#pragma unroll
    for (int kc = 0; kc < 2; kc++)
#pragma unroll
        for (int ks = 0; ks < 6; ks++)
            afp[kc][ks] =
                *(const h4*)&A[(size_t)m * 192 + kc * 96 + ks * 16 + 4 * g];
    float xr[12];
#pragma unroll
    for (int nt = 0; nt < 3; nt++) {
#pragma unroll
        for (int j = 0; j < 4; j++)
            xr[nt * 4 + j] =
                x[(size_t)(ni * 48 + nt * 16 + 4 * g + j) * L_TOK + m];
    }

    STAGE(0, wp, 192);
    __syncthreads();
    STAGE(1, wp + 96, 192);
    v4f acc[3];
#pragma unroll
    for (int nt = 0; nt < 3; nt++) {
        acc[nt][0] = 0.f; acc[nt][1] = 0.f; acc[nt][2] = 0.f; acc[nt][3] = 0.f;
    }
    PROJ_CHUNK(0, 0);
    __syncthreads();
    STAGE(0, wf1, 96);
    PROJ_CHUNK(1, 1);
    float v[12];
    float s1 = 0.f, s2 = 0.f;
#pragma unroll
    for (int nt = 0; nt < 3; nt++) {
        const int c = ni * 48 + nt * 16 + 4 * g;
        float4 bv = *(const float4*)&bp[c];
        float a0 = acc[nt][0] + bv.x + xr[nt * 4 + 0];
        float a1 = acc[nt][1] + bv.y + xr[nt * 4 + 1];
        float a2 = acc[nt][2] + bv.z + xr[nt * 4 + 2];
        float a3 = acc[nt][3] + bv.w + xr[nt * 4 + 3];
        v[nt * 4 + 0] = a0; v[nt * 4 + 1] = a1;
        v[nt * 4 + 2] = a2; v[nt * 4 + 3] = a3;
        s1 += (a0 + a1) + (a2 + a3);
        s2 += (a0 * a0 + a1 * a1) + (a2 * a2 + a3 * a3);
    }
    s1 += __shfl_xor(s1, 16, 64);
    s1 += __shfl_xor(s1, 32, 64);
    s2 += __shfl_xor(s2, 16, 64);
    s2 += __shfl_xor(s2, 32, 64);
    if (g == 0) { red[ni][rl][0] = s1; red[ni][rl][1] = s2; }
    __syncthreads();
    {
        float t1 = red[0][rl][0] + red[1][rl][0];
        float t2 = red[0][rl][1] + red[1][rl][1];
        float mean = t1 * (1.f / 96.f);
        float var = t2 * (1.f / 96.f) - mean * mean;
        float rstd = rsqrtf(var + 1e-5f);
#pragma unroll
        for (int nt = 0; nt < 3; nt++) {
            const int c = ni * 48 + nt * 16 + 4 * g;
            float4 gg = *(const float4*)&g2[c];
            float4 bb = *(const float4*)&b2[c];
            h4 o = pack4((v[nt * 4 + 0] - mean) * rstd * gg.x + bb.x,
                         (v[nt * 4 + 1] - mean) * rstd * gg.y + bb.y,
                         (v[nt * 4 + 2] - mean) * rstd * gg.z + bb.z,
                         (v[nt * 4 + 3] - mean) * rstd * gg.w + bb.w);
            *(h4*)&n2_lds[rl * WSTRIDE + c] = o;
        }
    }
    STAGE(1, wf1 + 96 * 96, 96);
    __syncthreads();
    h4 hf[4][3];
    FC1_CHUNK(0, 0);
    __syncthreads();
    STAGE(0, wf1 + 2 * 96 * 96, 96);
    FC1_CHUNK(1, 1);
    __syncthreads();
    STAGE(1, wf1 + 3 * 96 * 96, 96);
    FC1_CHUNK(0, 2);
    __syncthreads();
    STAGE(0, wf2, 384);
    FC1_CHUNK(1, 3);
    __syncthreads();
    v4f o6[6];
#pragma unroll
    for (int nt = 0; nt < 6; nt++) {
        o6[nt][0] = 0.f; o6[nt][1] = 0.f; o6[nt][2] = 0.f; o6[nt][3] = 0.f;
    }
    STAGE(1, wf2 + 96, 384);
    FC2_CHUNK(0, 0);
    __syncthreads();
    STAGE(0, wf2 + 192, 384);
    FC2_CHUNK(1, 1);
    __syncthreads();
    STAGE(1, wf2 + 288, 384);
    FC2_CHUNK(0, 2);
    __syncthreads();
    FC2_CHUNK(1, 3);
    __syncthreads();

    if (ni == 0) {
#pragma unroll
        for (int nt = 0; nt < 6; nt++) {
#pragma unroll
            for (int j = 0; j < 4; j++) {
                const int c = nt * 16 + 4 * g + j;
                float val = o6[nt][j] + f2b[c];
                if (nt < 3) val += v[nt * 4 + j];
                sh[c * 34 + rl] = val;
            }
        }
    }
    __syncthreads();
    if (ni == 1) {
#pragma unroll
        for (int nt = 0; nt < 6; nt++) {
#pragma unroll
            for (int j = 0; j < 4; j++) {
                const int c = nt * 16 + 4 * g + j;
                float val = o6[nt][j];
                if (nt >= 3) val += v[(nt - 3) * 4 + j];
                sh[c * 34 + rl] += val;
            }
        }
    }
    __syncthreads();
    const int hh = m0 >> 9, ww0 = (m0 >> 4) & 31;
#pragma unroll
    for (int i = 0; i < 6; i++) {
        int task = t + i * 256;
        int n = task >> 4, dd = task & 15;
        float2 ov;
        ov.x = sh[n * 34 + dd];
        ov.y = sh[n * 34 + 16 + dd];
        *(float2*)&out[(size_t)n * L_TOK + dd * 1024 + hh * 32 + ww0] = ov;
    }
}

// ---------------------------------------------------------------------------
// HW attention (R18/R19-verified): XCD-local staging grid (128 slices, 8 qb),
// K + V^T both LDS-resident.
// ---------------------------------------------------------------------------
__global__ __launch_bounds__(256) void attn_hw_kernel(
    const _Float16* __restrict__ Qp, const _Float16* __restrict__ Kp,
    const _Float16* __restrict__ VTp, _Float16* __restrict__ o_cat) {
    __shared__ _Float16 K_lds[1024 * 12];
    __shared__ _Float16 VT_lds[13 * 1032];
    const int t = threadIdx.x;
    const int sliceid = blockIdx.x;
    const int qb = blockIdx.y;
    const int d = sliceid >> 3, h = sliceid & 7;
    const size_t tokbase = (size_t)d * HW_N;
    const int hoff = h * HD;
    const size_t slice = (size_t)sliceid;

    {
        const float4* Kg = (const float4*)(Kp + slice * 12288);
        float4* K4 = (float4*)K_lds;
#pragma unroll
        for (int i = 0; i < 6; i++) K4[t + i * 256] = Kg[t + i * 256];
        const float4* Vg = (const float4*)(VTp + slice * 12288);
#pragma unroll
        for (int i = 0; i < 6; i++) {
            int off = t + i * 256;
            int row = off >> 7, col = (off & 127) * 8;
            *(float4*)&VT_lds[row * 1032 + col] = Vg[off];
        }
        unsigned* zp = (unsigned*)&VT_lds[12 * 1032];
        zp[t] = 0x3C003C00u; zp[t + 256] = 0x3C003C00u;
        if (t < 4) zp[t + 512] = 0x3C003C00u;
    }

    const int lane = t & 63, w = t >> 6, g = lane >> 4, r = lane & 15;
    const int q0w = qb * 128 + w * 32;

    h4 zf; zf[0] = zf[1] = zf[2] = zf[3] = (_Float16)0.f;
    h4 qf[2];
    {
        const _Float16* Qbase = Qp + (slice * 1024 + q0w + r) * 12 + 4 * g;
#pragma unroll
        for (int qt = 0; qt < 2; qt++) {
            qf[qt] = (g < 3) ? *(const h4*)(Qbase + qt * 16 * 12) : zf;
        }
    }

    v4f acc[2];
#pragma unroll
    for (int qt = 0; qt < 2; qt++) {
        acc[qt][0] = acc[qt][1] = acc[qt][2] = acc[qt][3] = 0.f;
    }

    const int koff = r * 12 + 4 * g;
    const int rowc = (r < 12) ? r : 12;
    const int voff = rowc * 1032 + 4 * g;

    __syncthreads();

    v4f zero; zero[0] = zero[1] = zero[2] = zero[3] = 0.f;
#pragma unroll 4
    for (int kt = 0; kt < HW_N / 16; kt++) {
        h4 kf = (g < 3) ? *(const h4*)&K_lds[kt * 192 + koff] : zf;
        h4 vf = *(const h4*)&VT_lds[voff + kt * 16];
#pragma unroll
        for (int qt = 0; qt < 2; qt++) {
            v4f s = __builtin_amdgcn_mfma_f32_16x16x16f16(kf, qf[qt], zero, 0, 0, 0);
            h4 pf = pack4(fast_exp2(s[0]), fast_exp2(s[1]),
                          fast_exp2(s[2]), fast_exp2(s[3]));
            acc[qt] = __builtin_amdgcn_mfma_f32_16x16x16f16(vf, pf, acc[qt], 0, 0, 0);
        }
    }

#pragma unroll
    for (int qt = 0; qt < 2; qt++) {
        float denom = __shfl(acc[qt][0], 48 + r, 64);
        float rs = 1.f / denom;
        if (g < 3) {
            _Float16* op =
                o_cat + (tokbase + q0w + qt * 16 + r) * 192 + hoff + 4 * g;
            h4 o;
            o[0] = (_Float16)(acc[qt][0] * rs);
            o[1] = (_Float16)(acc[qt][1] * rs);
            o[2] = (_Float16)(acc[qt][2] * rs);
            o[3] = (_Float16)(acc[qt][3] * rs);
            *(h4*)op = o;
        }
    }
}

// ---------------------------------------------------------------------------
// Temporal attention from T_pack.
// ---------------------------------------------------------------------------
__global__ __launch_bounds__(256) void attn_t_kernel(
    const _Float16* __restrict__ Tp, _Float16* __restrict__ o_cat) {
    int gid = blockIdx.x * 256 + threadIdx.x;
    int hw = gid >> 7;
    int h = (gid >> 4) & 7;
    int q = gid & 15;
    const int hoff = h * HD;
    const _Float16* base = Tp + (size_t)(hw * 16) * 288;

    float qr[HD];
    {
        const _Float16* p = base + q * 288 + hoff;
        h4 a = *(const h4*)p, b = *(const h4*)(p + 4), c = *(const h4*)(p + 8);
#pragma unroll
        for (int e = 0; e < 4; e++) {
            qr[e] = (float)a[e]; qr[4 + e] = (float)b[e]; qr[8 + e] = (float)c[e];
        }
    }
    float s[D_DIM];
    float mx = -1e30f;
#pragma unroll
    for (int j = 0; j < D_DIM; j++) {
        const _Float16* kp = base + j * 288 + 96 + hoff;
        h4 a = *(const h4*)kp, b = *(const h4*)(kp + 4), c = *(const h4*)(kp + 8);
        float dot = 0.f;
#pragma unroll
        for (int e = 0; e < 4; e++) {
            dot += qr[e] * (float)a[e] + qr[4 + e] * (float)b[e] +
                   qr[8 + e] * (float)c[e];
        }
        s[j] = dot;
        mx = fmaxf(mx, dot);
    }
    float sum = 0.f;
#pragma unroll
    for (int j = 0; j < D_DIM; j++) {
        s[j] = fast_exp2(s[j] - mx);
        sum += s[j];
    }
    float rs = 1.f / sum;
    float o[HD];
#pragma unroll
    for (int e = 0; e < HD; e++) o[e] = 0.f;
#pragma unroll
    for (int j = 0; j < D_DIM; j++) {
        const _Float16* vp = base + j * 288 + 192 + hoff;
        h4 a = *(const h4*)vp, b = *(const h4*)(vp + 4), c = *(const h4*)(vp + 8);
        float p = s[j];
#pragma unroll
        for (int e = 0; e < 4; e++) {
            o[e] += p * (float)a[e];
            o[4 + e] += p * (float)b[e];
            o[8 + e] += p * (float)c[e];
        }
    }
    _Float16* op = o_cat + ((size_t)hw * D_DIM + q) * 192 + 96 + hoff;
#pragma unroll
    for (int e = 0; e < HD; e += 4) {
        h4 a;
        a[0] = (_Float16)(o[e] * rs); a[1] = (_Float16)(o[e + 1] * rs);
        a[2] = (_Float16)(o[e + 2] * rs); a[3] = (_Float16)(o[e + 3] * rs);
        *(h4*)(op + e) = a;
    }
}

// ---------------------------------------------------------------------------
extern "C" void kernel_launch(void* const* d_in, const int* in_sizes, int n_in,
                              void* d_out, int out_size, void* d_ws,
                              size_t ws_size, hipStream_t stream) {
    const float* x         = (const float*)d_in[0];
    const float* norm1_g   = (const float*)d_in[1];
    const float* norm1_b   = (const float*)d_in[2];
    const float* qkv_hw_w  = (const float*)d_in[3];
    const float* proj_hw_w = (const float*)d_in[4];
    const float* proj_hw_b = (const float*)d_in[5];
    const float* qkv_t_w   = (const float*)d_in[6];
    const float* proj_t_w  = (const float*)d_in[7];
    const float* proj_t_b  = (const float*)d_in[8];
    const float* norm2_g   = (const float*)d_in[9];
    const float* norm2_b   = (const float*)d_in[10];
    const float* fc1_w     = (const float*)d_in[11];
    const float* fc1_b     = (const float*)d_in[12];
    const float* fc2_w     = (const float*)d_in[13];
    const float* fc2_b     = (const float*)d_in[14];
    float* out = (float*)d_out;

    // workspace layout
    char* ws = (char*)d_ws;
    _Float16* n1h    = (_Float16*)ws;                          // L*96 f16
    _Float16* o_cat  = n1h + (size_t)L_TOK * C_DIM;            // L*192 f16
    float*    out_res= (float*)(o_cat + (size_t)L_TOK * 192);  // (unused)
    _Float16* packs  = (_Float16*)(out_res + (size_t)L_TOK * C_DIM);
    _Float16* Qp     = packs;                                  // 16*8*1024*12
    _Float16* Kp     = Qp + 1572864;
    _Float16* VTp    = Kp + 1572864;
    _Float16* Tp     = VTp + 1572864;                          // L*288
    _Float16* wq     = Tp + (size_t)L_TOK * 288;               // 55296
    _Float16* wp     = wq + 55296;
    _Float16* wf1    = wp + 18432;
    _Float16* wf2    = wf1 + 36864;
    float*    bp     = (float*)(wf2 + 36864);

    // 1. LN1 + weight convert (merged)
    prep_kernel<<<641, 256, 0, stream>>>(x, norm1_g, norm1_b, n1h,
                                         qkv_hw_w, qkv_t_w, proj_hw_w,
                                         proj_t_w, proj_hw_b, proj_t_b,
                                         fc1_w, fc2_w, wq, wp, wf1, wf2, bp);
    // 2. fused qkv GEMM with packed scatter
    gemm_qkv<<<dim3(L_TOK / GBM, 576 / GBN), 256, 0, stream>>>(
        n1h, wq, Qp, Kp, VTp, Tp);
    // 3. HW attention (XCD-local slice staging)
    attn_hw_kernel<<<dim3(128, 8), 256, 0, stream>>>(Qp, Kp, VTp, o_cat);
    // 4. T attention
    attn_t_kernel<<<(HW_N * N_HEADS * D_DIM) / 256, 256, 0, stream>>>(Tp, o_cat);
    // 5. fused MLP v6
    fused_mlp<<<512, 256, 0, stream>>>(
        o_cat, wp, bp, x, norm2_g, norm2_b, wf1, fc1_b, wf2, fc2_b, out);
}